// Round 1
// baseline (1403.587 us; speedup 1.0000x reference)
//
#include <hip/hip_runtime.h>

typedef __attribute__((ext_vector_type(8))) short bf16x8;
typedef __attribute__((ext_vector_type(4))) float f32x4;

#define MFMA_BF16(a,b,c) __builtin_amdgcn_mfma_f32_16x16x32_bf16(a,b,c,0,0,0)

#define H_ 16
#define DH 64
#define LQ 2112      // 2048 S-queries + 64 NS
#define LK 4160      // 4096 S-keys + 64 NS
#define QOFF 2048    // q_pos = QOFF + q_row
#define DM 1024
#define NO 3072

__device__ __forceinline__ unsigned short f2bf(float f) {
  union { float f; unsigned u; } v; v.f = f;
  unsigned u = v.u;
  return (unsigned short)((u + 0x7FFFu + ((u >> 16) & 1u)) >> 16);
}

// ---------------- fp32 -> bf16 convert of x ----------------
__global__ __launch_bounds__(256) void cvt_x(const float* __restrict__ x,
                                             unsigned short* __restrict__ xb) {
  int i = blockIdx.x * 256 + threadIdx.x;   // 4160*1024/4 elements of float4
  float4 f = ((const float4*)x)[i];
  ushort4 o;
  o.x = f2bf(f.x); o.y = f2bf(f.y); o.z = f2bf(f.z); o.w = f2bf(f.w);
  ((ushort4*)xb)[i] = o;
}

// ---------------- transpose fp32 (R x C) -> bf16 (C x R) ----------------
__global__ __launch_bounds__(256) void transp_bf(const float* __restrict__ in,
                                                 unsigned short* __restrict__ out,
                                                 int R, int C) {
  __shared__ float t[32][33];
  int c0 = blockIdx.x * 32, r0 = blockIdx.y * 32;
  #pragma unroll
  for (int i = threadIdx.y; i < 32; i += 8)
    t[i][threadIdx.x] = in[(size_t)(r0 + i) * C + c0 + threadIdx.x];
  __syncthreads();
  #pragma unroll
  for (int i = threadIdx.y; i < 32; i += 8)
    out[(size_t)(c0 + i) * R + r0 + threadIdx.x] = f2bf(t[threadIdx.x][i]);
}

// ---------------- qkv_NS: per-position GEMV, fp32, atomic d-split ----------------
// grid (3 oc, 4 dc, 64 n), block 256
__global__ __launch_bounds__(256) void qkv_ns_k(const float* __restrict__ x,
                                                const float* __restrict__ W_NS,
                                                float* __restrict__ qkvNS) {
  int oc = blockIdx.x, dc = blockIdx.y, n = blockIdx.z;
  __shared__ float xs[256];
  xs[threadIdx.x] = x[(size_t)(4096 + n) * DM + dc * 256 + threadIdx.x];
  __syncthreads();
  int o0 = oc * 1024 + threadIdx.x * 4;
  const float* W = W_NS + ((size_t)n * DM + dc * 256) * NO + o0;
  float a0 = 0.f, a1 = 0.f, a2 = 0.f, a3 = 0.f;
  #pragma unroll 4
  for (int d = 0; d < 256; ++d) {
    float xv = xs[d];
    float4 w = *(const float4*)(W + (size_t)d * NO);
    a0 = fmaf(xv, w.x, a0); a1 = fmaf(xv, w.y, a1);
    a2 = fmaf(xv, w.z, a2); a3 = fmaf(xv, w.w, a3);
  }
  float* dst = qkvNS + (size_t)n * NO + o0;
  atomicAdd(dst + 0, a0); atomicAdd(dst + 1, a1);
  atomicAdd(dst + 2, a2); atomicAdd(dst + 3, a3);
}

// ---------------- scatter qkv_NS into head-major Q/K/V bf16 buffers ----------------
__global__ __launch_bounds__(256) void scatter_ns(const float* __restrict__ qkvNS,
                                                  unsigned short* __restrict__ Qb,
                                                  unsigned short* __restrict__ Kb,
                                                  unsigned short* __restrict__ Vb) {
  int i = blockIdx.x * 256 + threadIdx.x;  // 64*3072
  int n = i / NO, o = i - n * NO;
  float v = qkvNS[i];
  int h = (o & 1023) >> 6, dh = o & 63;
  if (o < 1024)       Qb[((size_t)h * LQ + 2048 + n) * DH + dh] = f2bf(v * 0.125f);
  else if (o < 2048)  Kb[((size_t)h * LK + 4096 + n) * DH + dh] = f2bf(v);
  else                Vb[((size_t)h * LK + 4096 + n) * DH + dh] = f2bf(v);
}

// ---------------- 128x128 bf16 MFMA GEMM: qkv_S ----------------
// A = xb (4096 x 1024), BT = WST (3072 x 1024). grid (32, 24), block 256.
__global__ __launch_bounds__(256) void gemm_qkv(const unsigned short* __restrict__ A,
                                                const unsigned short* __restrict__ BT,
                                                unsigned short* __restrict__ Qb,
                                                unsigned short* __restrict__ Kb,
                                                unsigned short* __restrict__ Vb) {
  __shared__ unsigned short At[128 * 32];
  __shared__ unsigned short Bt[128 * 32];
  int tm = blockIdx.x * 128, tn = blockIdx.y * 128;
  int tid = threadIdx.x, wave = tid >> 6, lane = tid & 63;
  int col = lane & 15, quad = lane >> 4;
  int wr = (wave & 1) * 64, wc = (wave >> 1) * 64;
  int srow = tid >> 2, spart = (tid & 3) * 8;

  f32x4 acc[4][4] = {};

  for (int kb = 0; kb < DM; kb += 32) {
    __syncthreads();
    *(uint4*)&At[srow * 32 + spart]        = *(const uint4*)&A[(size_t)(tm + srow) * DM + kb + spart];
    *(uint4*)&At[(srow + 64) * 32 + spart] = *(const uint4*)&A[(size_t)(tm + srow + 64) * DM + kb + spart];
    *(uint4*)&Bt[srow * 32 + spart]        = *(const uint4*)&BT[(size_t)(tn + srow) * DM + kb + spart];
    *(uint4*)&Bt[(srow + 64) * 32 + spart] = *(const uint4*)&BT[(size_t)(tn + srow + 64) * DM + kb + spart];
    __syncthreads();
    bf16x8 af[4], bfr[4];
    #pragma unroll
    for (int i = 0; i < 4; ++i) {
      af[i]  = *(const bf16x8*)&At[(wr + i * 16 + col) * 32 + quad * 8];
      bfr[i] = *(const bf16x8*)&Bt[(wc + i * 16 + col) * 32 + quad * 8];
    }
    #pragma unroll
    for (int i = 0; i < 4; ++i)
      #pragma unroll
      for (int j = 0; j < 4; ++j)
        acc[i][j] = MFMA_BF16(af[i], bfr[j], acc[i][j]);
  }

  #pragma unroll
  for (int i = 0; i < 4; ++i)
    #pragma unroll
    for (int j = 0; j < 4; ++j)
      #pragma unroll
      for (int r = 0; r < 4; ++r) {
        int m = tm + wr + i * 16 + quad * 4 + r;
        int n = tn + wc + j * 16 + col;
        float v = acc[i][j][r];
        int h = (n & 1023) >> 6, dh = n & 63;
        if (n < 1024) {
          if (m >= QOFF) Qb[((size_t)h * LQ + (m - QOFF)) * DH + dh] = f2bf(v * 0.125f);
        } else if (n < 2048) {
          Kb[((size_t)h * LK + m) * DH + dh] = f2bf(v);
        } else {
          Vb[((size_t)h * LK + m) * DH + dh] = f2bf(v);
        }
      }
}

// ---------------- flash attention ----------------
// grid (33 q-tiles, 16 heads), block 256 (4 waves x 16 q-rows), 32-key tiles
__global__ __launch_bounds__(256) void attn(const unsigned short* __restrict__ Qb,
                                            const unsigned short* __restrict__ Kb,
                                            const unsigned short* __restrict__ Vb,
                                            unsigned short* __restrict__ Ob) {
  __shared__ unsigned short Kt[32 * 64];     // [k_local][dh]
  __shared__ unsigned short Vt[64 * 32];     // [dh][k_local]
  __shared__ unsigned short Pt[4][16 * 32];  // per-wave P [q_local][k_local]
  int h = blockIdx.y;
  int qb = blockIdx.x * 64;
  int tid = threadIdx.x, wave = tid >> 6, lane = tid & 63;
  int col = lane & 15, quad = lane >> 4;
  const unsigned short* Qh = Qb + (size_t)h * LQ * DH;
  const unsigned short* Kh = Kb + (size_t)h * LK * DH;
  const unsigned short* Vh = Vb + (size_t)h * LK * DH;

  int qrow = qb + wave * 16 + col;           // A-frag m index = lane&15
  bf16x8 aq0 = *(const bf16x8*)&Qh[qrow * DH + quad * 8];
  bf16x8 aq1 = *(const bf16x8*)&Qh[qrow * DH + 32 + quad * 8];

  f32x4 oacc[4] = {};
  float m_i[4] = {-3e38f, -3e38f, -3e38f, -3e38f};
  float l_i[4] = {0.f, 0.f, 0.f, 0.f};

  int skl = tid >> 3;            // 0..31
  int sdc = (tid & 7) * 8;       // 0..56

  int nkt = (QOFF + qb + 64) >> 5;
  for (int kt = 0; kt < nkt; ++kt) {
    int kb = kt << 5;
    __syncthreads();
    {  // stage K (straight) and V (transposed)
      *(uint4*)&Kt[skl * 64 + sdc] = *(const uint4*)&Kh[(size_t)(kb + skl) * DH + sdc];
      unsigned short tmp[8];
      *(uint4*)tmp = *(const uint4*)&Vh[(size_t)(kb + skl) * DH + sdc];
      #pragma unroll
      for (int j = 0; j < 8; ++j) Vt[(sdc + j) * 32 + skl] = tmp[j];
    }
    __syncthreads();

    f32x4 s0 = {}, s1 = {};
    {
      bf16x8 b00 = *(const bf16x8*)&Kt[col * 64 + quad * 8];
      bf16x8 b01 = *(const bf16x8*)&Kt[col * 64 + 32 + quad * 8];
      bf16x8 b10 = *(const bf16x8*)&Kt[(16 + col) * 64 + quad * 8];
      bf16x8 b11 = *(const bf16x8*)&Kt[(16 + col) * 64 + 32 + quad * 8];
      s0 = MFMA_BF16(aq0, b00, s0); s0 = MFMA_BF16(aq1, b01, s0);
      s1 = MFMA_BF16(aq0, b10, s1); s1 = MFMA_BF16(aq1, b11, s1);
    }

    float alpha[4];
    #pragma unroll
    for (int r = 0; r < 4; ++r) {
      int q = qb + wave * 16 + quad * 4 + r;
      int kmax = QOFF + q;  // inclusive causal bound (scale pre-folded into Q)
      float v0 = (kb + col      <= kmax) ? s0[r] : -3e38f;
      float v1 = (kb + 16 + col <= kmax) ? s1[r] : -3e38f;
      float t = fmaxf(v0, v1);
      t = fmaxf(t, __shfl_xor(t, 1));
      t = fmaxf(t, __shfl_xor(t, 2));
      t = fmaxf(t, __shfl_xor(t, 4));
      t = fmaxf(t, __shfl_xor(t, 8));
      float mn = fmaxf(m_i[r], t);
      alpha[r] = __expf(m_i[r] - mn);
      m_i[r] = mn;
      float e0 = __expf(v0 - mn);
      float e1 = __expf(v1 - mn);
      float su = e0 + e1;
      su += __shfl_xor(su, 1);
      su += __shfl_xor(su, 2);
      su += __shfl_xor(su, 4);
      su += __shfl_xor(su, 8);
      l_i[r] = l_i[r] * alpha[r] + su;
      Pt[wave][(quad * 4 + r) * 32 + col]      = f2bf(e0);
      Pt[wave][(quad * 4 + r) * 32 + 16 + col] = f2bf(e1);
    }
    #pragma unroll
    for (int dt = 0; dt < 4; ++dt)
      #pragma unroll
      for (int r = 0; r < 4; ++r) oacc[dt][r] *= alpha[r];

    asm volatile("s_waitcnt lgkmcnt(0)" ::: "memory");  // cross-lane LDS visibility (same wave)
    bf16x8 ap = *(const bf16x8*)&Pt[wave][col * 32 + quad * 8];
    #pragma unroll
    for (int dt = 0; dt < 4; ++dt) {
      bf16x8 bv = *(const bf16x8*)&Vt[(dt * 16 + col) * 32 + quad * 8];
      oacc[dt] = MFMA_BF16(ap, bv, oacc[dt]);
    }
  }

  #pragma unroll
  for (int r = 0; r < 4; ++r) {
    int q = qb + wave * 16 + quad * 4 + r;
    float inv = 1.0f / l_i[r];
    #pragma unroll
    for (int dt = 0; dt < 4; ++dt)
      Ob[(size_t)q * DM + h * DH + dt * 16 + col] = f2bf(oacc[dt][r] * inv);
  }
}

// ---------------- out-projection GEMM: (2112x1024) @ (1024x1024) -> fp32 ----------------
// grid (17, 8)
__global__ __launch_bounds__(256) void gemm_out_k(const unsigned short* __restrict__ A,
                                                  const unsigned short* __restrict__ BT,
                                                  float* __restrict__ C) {
  __shared__ unsigned short At[128 * 32];
  __shared__ unsigned short Bt[128 * 32];
  int tm = blockIdx.x * 128, tn = blockIdx.y * 128;
  int tid = threadIdx.x, wave = tid >> 6, lane = tid & 63;
  int col = lane & 15, quad = lane >> 4;
  int wr = (wave & 1) * 64, wc = (wave >> 1) * 64;
  int srow = tid >> 2, spart = (tid & 3) * 8;
  int ar0 = min(tm + srow, LQ - 1);
  int ar1 = min(tm + srow + 64, LQ - 1);

  f32x4 acc[4][4] = {};

  for (int kb = 0; kb < DM; kb += 32) {
    __syncthreads();
    *(uint4*)&At[srow * 32 + spart]        = *(const uint4*)&A[(size_t)ar0 * DM + kb + spart];
    *(uint4*)&At[(srow + 64) * 32 + spart] = *(const uint4*)&A[(size_t)ar1 * DM + kb + spart];
    *(uint4*)&Bt[srow * 32 + spart]        = *(const uint4*)&BT[(size_t)(tn + srow) * DM + kb + spart];
    *(uint4*)&Bt[(srow + 64) * 32 + spart] = *(const uint4*)&BT[(size_t)(tn + srow + 64) * DM + kb + spart];
    __syncthreads();
    bf16x8 af[4], bfr[4];
    #pragma unroll
    for (int i = 0; i < 4; ++i) {
      af[i]  = *(const bf16x8*)&At[(wr + i * 16 + col) * 32 + quad * 8];
      bfr[i] = *(const bf16x8*)&Bt[(wc + i * 16 + col) * 32 + quad * 8];
    }
    #pragma unroll
    for (int i = 0; i < 4; ++i)
      #pragma unroll
      for (int j = 0; j < 4; ++j)
        acc[i][j] = MFMA_BF16(af[i], bfr[j], acc[i][j]);
  }

  #pragma unroll
  for (int i = 0; i < 4; ++i)
    #pragma unroll
    for (int j = 0; j < 4; ++j)
      #pragma unroll
      for (int r = 0; r < 4; ++r) {
        int m = tm + wr + i * 16 + quad * 4 + r;
        int n = tn + wc + j * 16 + col;
        if (m < LQ) C[(size_t)m * DM + n] = acc[i][j][r];
      }
}

extern "C" void kernel_launch(void* const* d_in, const int* in_sizes, int n_in,
                              void* d_out, int out_size, void* d_ws, size_t ws_size,
                              hipStream_t stream) {
  const float* x     = (const float*)d_in[0];
  const float* W_S   = (const float*)d_in[1];
  const float* W_NS  = (const float*)d_in[2];
  const float* W_out = (const float*)d_in[3];
  char* ws = (char*)d_ws;

  unsigned short* xb    = (unsigned short*)(ws + 0);          // 4160*1024 bf16
  unsigned short* WST   = (unsigned short*)(ws + 8519680);    // 3072*1024 bf16 (W_S^T)
  unsigned short* WOT   = (unsigned short*)(ws + 14811136);   // 1024*1024 bf16 (W_out^T)
  float*          qkvNS = (float*)(ws + 16908288);            // 64*3072 fp32
  unsigned short* Qb    = (unsigned short*)(ws + 17694720);   // 16*2112*64 bf16 (pre-scaled)
  unsigned short* Kb    = (unsigned short*)(ws + 22020096);   // 16*4160*64 bf16
  unsigned short* Vb    = (unsigned short*)(ws + 30539776);   // 16*4160*64 bf16
  unsigned short* Ob    = (unsigned short*)(ws + 39059456);   // 2112*1024 bf16
  float* out = (float*)d_out;

  hipMemsetAsync(qkvNS, 0, 64 * NO * sizeof(float), stream);
  cvt_x<<<4160, 256, 0, stream>>>(x, xb);
  transp_bf<<<dim3(96, 32), dim3(32, 8), 0, stream>>>(W_S, WST, 1024, 3072);
  transp_bf<<<dim3(32, 32), dim3(32, 8), 0, stream>>>(W_out, WOT, 1024, 1024);
  qkv_ns_k<<<dim3(3, 4, 64), 256, 0, stream>>>(x, W_NS, qkvNS);
  scatter_ns<<<768, 256, 0, stream>>>(qkvNS, Qb, Kb, Vb);
  gemm_qkv<<<dim3(32, 24), 256, 0, stream>>>(xb, WST, Qb, Kb, Vb);
  attn<<<dim3(33, 16), 256, 0, stream>>>(Qb, Kb, Vb, Ob);
  gemm_out_k<<<dim3(17, 8), 256, 0, stream>>>(Ob, WOT, out);
}